// Round 1
// baseline (1204.925 us; speedup 1.0000x reference)
//
#include <hip/hip_runtime.h>

#define NIN 10517

__device__ __forceinline__ float lrelu02(float x){ return x > 0.f ? x : 0.2f*x; }
__device__ __forceinline__ float fast_tanh(float x){ float e=__expf(2.f*x); return 1.f - 2.f/(e+1.f); }
__device__ __forceinline__ float fast_sig(float x){ return 1.f/(1.f+__expf(-x)); }

// ---------------- K1a: FC (384->256, relu) + Wh0 (256->128) + s,d per head ----------------
__global__ __launch_bounds__(256) void k_fc_gat(const float* __restrict__ inputs,
    const float* __restrict__ fc_w, const float* __restrict__ fc_b,
    const float* __restrict__ gat_w, const float* __restrict__ a_src, const float* __restrict__ a_dst,
    float* __restrict__ wh0_ws, float* __restrict__ sd_ws)
{
  __shared__ float xin[16][384];
  __shared__ float xfc[16][256];
  __shared__ float wh[16][128];
  const int tid = threadIdx.x;
  const int bt0 = blockIdx.x * 16;
  for (int idx = tid; idx < 16*384; idx += 256) {
    int r = idx / 384, f = idx - r*384;
    xin[r][f] = inputs[(size_t)(bt0+r)*NIN + 10133 + f];
  }
  __syncthreads();
  {
    float acc[16];
    float bj = fc_b[tid];
    #pragma unroll
    for (int r=0;r<16;r++) acc[r] = bj;
    for (int f=0; f<384; f++) {
      float wf = fc_w[f*256 + tid];
      #pragma unroll
      for (int r=0;r<16;r++) acc[r] = fmaf(xin[r][f], wf, acc[r]);
    }
    #pragma unroll
    for (int r=0;r<16;r++) xfc[r][tid] = fmaxf(acc[r], 0.f);
  }
  __syncthreads();
  {
    const int j2 = tid & 127, r0 = (tid >> 7) * 8;
    float acc[8];
    #pragma unroll
    for (int r=0;r<8;r++) acc[r] = 0.f;
    for (int f=0; f<256; f++) {
      float wf = gat_w[f*128 + j2];
      #pragma unroll
      for (int r=0;r<8;r++) acc[r] = fmaf(xfc[r0+r][f], wf, acc[r]);
    }
    #pragma unroll
    for (int r=0;r<8;r++) {
      wh[r0+r][j2] = acc[r];
      wh0_ws[(size_t)(bt0+r0+r)*128 + j2] = acc[r];
    }
  }
  __syncthreads();
  if (tid < 128) {
    const int r = tid >> 3, h = (tid >> 1) & 3, w = tid & 1;
    const float* av = w ? a_dst : a_src;
    float acc = 0.f;
    #pragma unroll
    for (int d=0; d<32; d++) acc = fmaf(wh[r][h*32+d], av[h*32+d], acc);
    sd_ws[(size_t)(bt0+r)*8 + w*4 + h] = acc;
  }
}

// ---------------- K1b: adjacency stats + closed-form alpha + x_gat ----------------
__global__ __launch_bounds__(256) void k_alpha(const float* __restrict__ inputs,
    const float* __restrict__ wh0_ws, const float* __restrict__ sd_ws, float* __restrict__ xgat_ws)
{
  __shared__ int cnt[100];
  __shared__ int a0f[100];
  __shared__ float alpha[4][100];
  __shared__ float wh0[128];
  __shared__ float sdl[8];
  const int tid = threadIdx.x;
  const size_t bt = blockIdx.x;
  if (tid < 128) wh0[tid] = wh0_ws[bt*128 + tid];
  if (tid < 8) sdl[tid] = sd_ws[bt*8 + tid];
  const float* adj = inputs + bt*NIN + 132;
  const int wv = tid >> 6, lane = tid & 63;
  // one wave per row: ballot-based count, no atomics
  for (int i = wv; i < 100; i += 4) {
    float v0 = adj[i*100 + lane];
    int pred0 = (lane != 0) && ((v0 > 0.f) || (lane == i));
    unsigned long long b0 = __ballot(pred0);
    int pred1 = 0;
    if (lane < 36) {
      float v1 = adj[i*100 + 64 + lane];
      pred1 = (v1 > 0.f) || ((64 + lane) == i);
    }
    unsigned long long b1 = __ballot(pred1);
    if (lane == 0) {
      cnt[i] = __popcll(b0) + __popcll(b1);
      a0f[i] = (v0 > 0.f) ? 1 : 0;
    }
  }
  __syncthreads();
  for (int idx = tid; idx < 400; idx += 256) {
    int h = idx / 100, i = idx - h*100;
    float s = sdl[h], d = sdl[4+h];
    float a;
    if (i == 0) {
      float ea = __expf(lrelu02(s + d));
      float eb = __expf(lrelu02(s));
      a = ea / (ea + (float)cnt[0] * eb);
    } else if (a0f[i]) {
      float ed = __expf(lrelu02(d));
      a = ed / (ed + (float)cnt[i]);
    } else {
      a = 0.f;
    }
    alpha[h][i] = a;
  }
  __syncthreads();
  if (tid < 128) {
    const int h = tid >> 5;
    const float w = wh0[tid];
    float sum = 0.f;
    for (int i=0;i<100;i++) {
      float t = alpha[h][i] * w;
      sum += (t > 0.f) ? t : (__expf(t) - 1.f);  // elu
    }
    xgat_ws[bt*128 + tid] = sum * 0.01f;  // mean over N=100
  }
}

// ---------------- K1c: gi = x_gat @ gru_wi + gru_bi ----------------
__global__ __launch_bounds__(384) void k_gi(const float* __restrict__ xgat_ws,
    const float* __restrict__ gru_wi, const float* __restrict__ gru_bi, float* __restrict__ gi_ws)
{
  __shared__ float xg[16][128];
  const int tid = threadIdx.x;
  const int bt0 = blockIdx.x * 16;
  for (int idx = tid; idx < 16*128; idx += 384) {
    int r = idx >> 7, f = idx & 127;
    xg[r][f] = xgat_ws[(size_t)(bt0+r)*128 + f];
  }
  __syncthreads();
  float acc[16];
  float bj = gru_bi[tid];
  #pragma unroll
  for (int r=0;r<16;r++) acc[r] = bj;
  for (int f=0; f<128; f++) {
    float wf = gru_wi[f*384 + tid];
    #pragma unroll
    for (int r=0;r<16;r++) acc[r] = fmaf(xg[r][f], wf, acc[r]);
  }
  #pragma unroll
  for (int r=0;r<16;r++) gi_ws[(size_t)(bt0+r)*384 + tid] = acc[r];
}

// ---------------- K1d: transpose gru_wh (128x384 -> 384x128) for per-lane float4 reads ----------------
__global__ void k_whT(const float* __restrict__ gru_wh, float* __restrict__ whT) {
  int idx = blockIdx.x * 256 + threadIdx.x;
  if (idx < 384*128) {
    int jj = idx >> 7, k = idx & 127;
    whT[idx] = gru_wh[k*384 + jj];
  }
}

// ---------------- K2: sequential RK4-ODE + GRU scan, one block per batch element ----------------
__global__ __launch_bounds__(128, 1) void k_rnn(const float* __restrict__ inputs,
    const float* __restrict__ h0,
    const float* __restrict__ ode_w1, const float* __restrict__ ode_b1,
    const float* __restrict__ ode_w2, const float* __restrict__ ode_b2,
    const float* __restrict__ whT, const float* __restrict__ gru_bh,
    const float* __restrict__ gi_ws, float* __restrict__ hs_ws, float* __restrict__ hT_out)
{
  __shared__ __align__(16) float vbuf[128];
  __shared__ __align__(16) float ubuf[128];
  const int j = threadIdx.x;
  const int b = blockIdx.x;
  // ode weight columns live in VGPRs (static indexing via full unroll)
  float w1r[128], w2r[128];
  #pragma unroll
  for (int k=0;k<128;k++) w1r[k] = ode_w1[k*128 + j];
  #pragma unroll
  for (int k=0;k<128;k++) w2r[k] = ode_w2[k*128 + j];
  const float b1 = ode_b1[j], b2 = ode_b2[j];
  const float bh0 = gru_bh[j], bh1 = gru_bh[128+j], bh2 = gru_bh[256+j];
  const float4* wa = reinterpret_cast<const float4*>(whT + (size_t)j*128);
  const float4* wb = reinterpret_cast<const float4*>(whT + (size_t)(j+128)*128);
  const float4* wc = reinterpret_cast<const float4*>(whT + (size_t)(j+256)*128);
  float h = h0[b*128 + j];

  auto feval = [&]() -> float {
    float a0=b1, a1=0.f, a2=0.f, a3=0.f;
    #pragma unroll
    for (int q=0;q<32;q++) {
      float4 hv = *reinterpret_cast<const float4*>(&vbuf[4*q]);
      a0 = fmaf(hv.x, w1r[4*q+0], a0);
      a1 = fmaf(hv.y, w1r[4*q+1], a1);
      a2 = fmaf(hv.z, w1r[4*q+2], a2);
      a3 = fmaf(hv.w, w1r[4*q+3], a3);
    }
    ubuf[j] = fast_tanh((a0+a1)+(a2+a3));
    __syncthreads();
    float c0=b2, c1=0.f, c2=0.f, c3=0.f;
    #pragma unroll
    for (int q=0;q<32;q++) {
      float4 hv = *reinterpret_cast<const float4*>(&ubuf[4*q]);
      c0 = fmaf(hv.x, w2r[4*q+0], c0);
      c1 = fmaf(hv.y, w2r[4*q+1], c1);
      c2 = fmaf(hv.z, w2r[4*q+2], c2);
      c3 = fmaf(hv.w, w2r[4*q+3], c3);
    }
    return fast_tanh((c0+c1)+(c2+c3));
  };

  for (int t=0; t<64; t++) {
    const size_t bt = (size_t)b*64 + t;
    const float dt = inputs[bt*NIN + 10132];
    vbuf[j] = h; __syncthreads();
    const float k1 = feval();
    vbuf[j] = fmaf(0.5f*dt, k1, h); __syncthreads();
    const float k2 = feval();
    vbuf[j] = fmaf(0.5f*dt, k2, h); __syncthreads();
    const float k3 = feval();
    vbuf[j] = fmaf(dt, k3, h); __syncthreads();
    const float k4 = feval();
    const float h_ode = fmaf(dt*(1.f/6.f), (k1 + 2.f*k2) + (2.f*k3 + k4), h);
    vbuf[j] = h_ode; __syncthreads();
    // gh = h_ode @ gru_wh + gru_bh (3 columns per thread, transposed weights, L2-resident)
    float ga = bh0, gb = bh1, gc = bh2;
    #pragma unroll 8
    for (int q=0;q<32;q++) {
      float4 hv = *reinterpret_cast<const float4*>(&vbuf[4*q]);
      float4 A = wa[q], Bv = wb[q], C = wc[q];
      ga += hv.x*A.x + hv.y*A.y + hv.z*A.z + hv.w*A.w;
      gb += hv.x*Bv.x + hv.y*Bv.y + hv.z*Bv.z + hv.w*Bv.w;
      gc += hv.x*C.x + hv.y*C.y + hv.z*C.z + hv.w*C.w;
    }
    const float ir  = gi_ws[bt*384 + j];
    const float iz  = gi_ws[bt*384 + 128 + j];
    const float inn = gi_ws[bt*384 + 256 + j];
    const float r = fast_sig(ir + ga);
    const float z = fast_sig(iz + gb);
    const float n = fast_tanh(inn + r*gc);
    h = (1.f - z)*n + z*h_ode;
    hs_ws[bt*128 + j] = h;
    __syncthreads();  // protect vbuf before next iteration's write
  }
  hT_out[b*128 + j] = h;
}

// ---------------- K3: logits + mask + value ----------------
__global__ __launch_bounds__(256) void k_head(const float* __restrict__ hs_ws,
    const float* __restrict__ act_w, const float* __restrict__ act_b,
    const float* __restrict__ val_w, const float* __restrict__ val_b,
    const float* __restrict__ inputs, float* __restrict__ out_logits, float* __restrict__ out_val)
{
  __shared__ float xr[16][128];
  const int tid = threadIdx.x;
  const int bt0 = blockIdx.x * 16;
  for (int idx = tid; idx < 16*128; idx += 256) {
    int r = idx >> 7, f = idx & 127;
    xr[r][f] = hs_ws[(size_t)(bt0+r)*128 + f];
  }
  __syncthreads();
  if (tid < 132) {
    float acc[16];
    float bj = act_b[tid];
    #pragma unroll
    for (int r=0;r<16;r++) acc[r] = bj;
    for (int f=0; f<128; f++) {
      float wf = act_w[f*132 + tid];
      #pragma unroll
      for (int r=0;r<16;r++) acc[r] = fmaf(xr[r][f], wf, acc[r]);
    }
    #pragma unroll
    for (int r=0;r<16;r++) {
      float m = inputs[(size_t)(bt0+r)*NIN + tid];
      out_logits[(size_t)(bt0+r)*132 + tid] = (m == 0.f) ? -1e10f : acc[r];
    }
  } else if (tid >= 136 && tid < 152) {
    int r = tid - 136;
    float acc = val_b[0];
    for (int f=0; f<128; f++) acc = fmaf(xr[r][f], val_w[f], acc);
    out_val[bt0 + r] = acc;
  }
}

extern "C" void kernel_launch(void* const* d_in, const int* in_sizes, int n_in,
                              void* d_out, int out_size, void* d_ws, size_t ws_size,
                              hipStream_t stream) {
  (void)in_sizes; (void)n_in; (void)out_size; (void)ws_size;
  const float* inputs = (const float*)d_in[0];
  const float* h0     = (const float*)d_in[1];
  const float* fc_w   = (const float*)d_in[2];
  const float* fc_b   = (const float*)d_in[3];
  const float* gat_w  = (const float*)d_in[4];
  const float* a_src  = (const float*)d_in[5];
  const float* a_dst  = (const float*)d_in[6];
  const float* ode_w1 = (const float*)d_in[7];
  const float* ode_b1 = (const float*)d_in[8];
  const float* ode_w2 = (const float*)d_in[9];
  const float* ode_b2 = (const float*)d_in[10];
  const float* gru_wi = (const float*)d_in[11];
  const float* gru_wh = (const float*)d_in[12];
  const float* gru_bi = (const float*)d_in[13];
  const float* gru_bh = (const float*)d_in[14];
  const float* act_w  = (const float*)d_in[15];
  const float* act_b  = (const float*)d_in[16];
  const float* val_w  = (const float*)d_in[17];
  const float* val_b  = (const float*)d_in[18];

  float* ws   = (float*)d_ws;
  float* wh0  = ws;              // 2048*128 = 262144
  float* sd   = ws + 262144;     // 2048*8   = 16384
  float* xgat = ws + 278528;     // 2048*128 = 262144
  float* gi   = ws + 540672;     // 2048*384 = 786432
  float* whT  = ws + 1327104;    // 384*128  = 49152
  float* hs   = ws + 1376256;    // 2048*128 = 262144

  float* out        = (float*)d_out;
  float* out_logits = out;            // 2048*132 = 270336
  float* out_hT     = out + 270336;   // 32*128   = 4096
  float* out_val    = out + 274432;   // 2048

  k_fc_gat<<<dim3(128), dim3(256), 0, stream>>>(inputs, fc_w, fc_b, gat_w, a_src, a_dst, wh0, sd);
  k_alpha <<<dim3(2048), dim3(256), 0, stream>>>(inputs, wh0, sd, xgat);
  k_gi    <<<dim3(128), dim3(384), 0, stream>>>(xgat, gru_wi, gru_bi, gi);
  k_whT   <<<dim3(192), dim3(256), 0, stream>>>(gru_wh, whT);
  k_rnn   <<<dim3(32),  dim3(128), 0, stream>>>(inputs, h0, ode_w1, ode_b1, ode_w2, ode_b2,
                                                whT, gru_bh, gi, hs, out_hT);
  k_head  <<<dim3(128), dim3(256), 0, stream>>>(hs, act_w, act_b, val_w, val_b, inputs,
                                                out_logits, out_val);
}

// Round 2
// 531.824 us; speedup vs baseline: 2.2656x; 2.2656x over previous
//
#include <hip/hip_runtime.h>

#define NIN 10517

__device__ __forceinline__ float lrelu02(float x){ return x > 0.f ? x : 0.2f*x; }
__device__ __forceinline__ float fast_tanh(float x){ float e=__expf(2.f*x); return 1.f - 2.f/(e+1.f); }
__device__ __forceinline__ float fast_sig(float x){ return 1.f/(1.f+__expf(-x)); }

// ---------------- K1a: FC (384->256, relu) + Wh0 (256->128) + s,d per head ----------------
__global__ __launch_bounds__(256) void k_fc_gat(const float* __restrict__ inputs,
    const float* __restrict__ fc_w, const float* __restrict__ fc_b,
    const float* __restrict__ gat_w, const float* __restrict__ a_src, const float* __restrict__ a_dst,
    float* __restrict__ wh0_ws, float* __restrict__ sd_ws)
{
  __shared__ float xin[16][384];
  __shared__ float xfc[16][256];
  __shared__ float wh[16][128];
  const int tid = threadIdx.x;
  const int bt0 = blockIdx.x * 16;
  for (int idx = tid; idx < 16*384; idx += 256) {
    int r = idx / 384, f = idx - r*384;
    xin[r][f] = inputs[(size_t)(bt0+r)*NIN + 10133 + f];
  }
  __syncthreads();
  {
    float acc[16];
    float bj = fc_b[tid];
    #pragma unroll
    for (int r=0;r<16;r++) acc[r] = bj;
    for (int f=0; f<384; f++) {
      float wf = fc_w[f*256 + tid];
      #pragma unroll
      for (int r=0;r<16;r++) acc[r] = fmaf(xin[r][f], wf, acc[r]);
    }
    #pragma unroll
    for (int r=0;r<16;r++) xfc[r][tid] = fmaxf(acc[r], 0.f);
  }
  __syncthreads();
  {
    const int j2 = tid & 127, r0 = (tid >> 7) * 8;
    float acc[8];
    #pragma unroll
    for (int r=0;r<8;r++) acc[r] = 0.f;
    for (int f=0; f<256; f++) {
      float wf = gat_w[f*128 + j2];
      #pragma unroll
      for (int r=0;r<8;r++) acc[r] = fmaf(xfc[r0+r][f], wf, acc[r]);
    }
    #pragma unroll
    for (int r=0;r<8;r++) {
      wh[r0+r][j2] = acc[r];
      wh0_ws[(size_t)(bt0+r0+r)*128 + j2] = acc[r];
    }
  }
  __syncthreads();
  if (tid < 128) {
    const int r = tid >> 3, h = (tid >> 1) & 3, w = tid & 1;
    const float* av = w ? a_dst : a_src;
    float acc = 0.f;
    #pragma unroll
    for (int d=0; d<32; d++) acc = fmaf(wh[r][h*32+d], av[h*32+d], acc);
    sd_ws[(size_t)(bt0+r)*8 + w*4 + h] = acc;
  }
}

// ---------------- K1b: adjacency stats + closed-form alpha + x_gat ----------------
__global__ __launch_bounds__(256) void k_alpha(const float* __restrict__ inputs,
    const float* __restrict__ wh0_ws, const float* __restrict__ sd_ws, float* __restrict__ xgat_ws)
{
  __shared__ int cnt[100];
  __shared__ int a0f[100];
  __shared__ float alpha[4][100];
  __shared__ float wh0[128];
  __shared__ float sdl[8];
  const int tid = threadIdx.x;
  const size_t bt = blockIdx.x;
  if (tid < 128) wh0[tid] = wh0_ws[bt*128 + tid];
  if (tid < 8) sdl[tid] = sd_ws[bt*8 + tid];
  const float* adj = inputs + bt*NIN + 132;
  const int wv = tid >> 6, lane = tid & 63;
  for (int i = wv; i < 100; i += 4) {
    float v0 = adj[i*100 + lane];
    int pred0 = (lane != 0) && ((v0 > 0.f) || (lane == i));
    unsigned long long b0 = __ballot(pred0);
    int pred1 = 0;
    if (lane < 36) {
      float v1 = adj[i*100 + 64 + lane];
      pred1 = (v1 > 0.f) || ((64 + lane) == i);
    }
    unsigned long long b1 = __ballot(pred1);
    if (lane == 0) {
      cnt[i] = __popcll(b0) + __popcll(b1);
      a0f[i] = (v0 > 0.f) ? 1 : 0;
    }
  }
  __syncthreads();
  for (int idx = tid; idx < 400; idx += 256) {
    int h = idx / 100, i = idx - h*100;
    float s = sdl[h], d = sdl[4+h];
    float a;
    if (i == 0) {
      float ea = __expf(lrelu02(s + d));
      float eb = __expf(lrelu02(s));
      a = ea / (ea + (float)cnt[0] * eb);
    } else if (a0f[i]) {
      float ed = __expf(lrelu02(d));
      a = ed / (ed + (float)cnt[i]);
    } else {
      a = 0.f;
    }
    alpha[h][i] = a;
  }
  __syncthreads();
  if (tid < 128) {
    const int h = tid >> 5;
    const float w = wh0[tid];
    float sum = 0.f;
    for (int i=0;i<100;i++) {
      float t = alpha[h][i] * w;
      sum += (t > 0.f) ? t : (__expf(t) - 1.f);  // elu
    }
    xgat_ws[bt*128 + tid] = sum * 0.01f;  // mean over N=100
  }
}

// ---------------- K1c: gi = x_gat @ gru_wi + gru_bi ----------------
__global__ __launch_bounds__(384) void k_gi(const float* __restrict__ xgat_ws,
    const float* __restrict__ gru_wi, const float* __restrict__ gru_bi, float* __restrict__ gi_ws)
{
  __shared__ float xg[16][128];
  const int tid = threadIdx.x;
  const int bt0 = blockIdx.x * 16;
  for (int idx = tid; idx < 16*128; idx += 384) {
    int r = idx >> 7, f = idx & 127;
    xg[r][f] = xgat_ws[(size_t)(bt0+r)*128 + f];
  }
  __syncthreads();
  float acc[16];
  float bj = gru_bi[tid];
  #pragma unroll
  for (int r=0;r<16;r++) acc[r] = bj;
  for (int f=0; f<128; f++) {
    float wf = gru_wi[f*384 + tid];
    #pragma unroll
    for (int r=0;r<16;r++) acc[r] = fmaf(xg[r][f], wf, acc[r]);
  }
  #pragma unroll
  for (int r=0;r<16;r++) gi_ws[(size_t)(bt0+r)*384 + tid] = acc[r];
}

// ---------------- K1d: transpose gru_wh (128x384 -> 384x128) ----------------
__global__ void k_whT(const float* __restrict__ gru_wh, float* __restrict__ whT) {
  int idx = blockIdx.x * 256 + threadIdx.x;
  if (idx < 384*128) {
    int jj = idx >> 7, k = idx & 127;
    whT[idx] = gru_wh[k*384 + jj];
  }
}

// ---------------- K2: RK4-ODE + GRU scan ----------------
// 256 threads/block, one block per batch element. Each output column j is
// owned by TWO lanes (same wave): p = lane>>5 picks which half of the K dim
// the lane accumulates; __shfl_xor(.,32) completes the dot. Weights per
// thread: 64+64 = 128 VGPRs (no spill; round-1's 256-VGPR version spilled).
__global__ __launch_bounds__(256, 1) void k_rnn(const float* __restrict__ inputs,
    const float* __restrict__ h0,
    const float* __restrict__ ode_w1, const float* __restrict__ ode_b1,
    const float* __restrict__ ode_w2, const float* __restrict__ ode_b2,
    const float* __restrict__ whT, const float* __restrict__ gru_bh,
    const float* __restrict__ gi_ws, float* __restrict__ hs_ws, float* __restrict__ hT_out)
{
  __shared__ __align__(16) float vbuf[128];
  __shared__ __align__(16) float ubuf[128];
  __shared__ __align__(16) float ghbuf[384];
  const int tid = threadIdx.x;
  const int wv = tid >> 6, lane = tid & 63;
  const int jj = lane & 31, p = lane >> 5;
  const int j = wv*32 + jj;            // output column, duplicated across p
  const int b = blockIdx.x;

  // half-column weights in VGPRs
  float w1h[64], w2h[64];
  #pragma unroll
  for (int k=0;k<64;k++) w1h[k] = ode_w1[(p*64+k)*128 + j];
  #pragma unroll
  for (int k=0;k<64;k++) w2h[k] = ode_w2[(p*64+k)*128 + j];
  const float b1 = ode_b1[j], b2 = ode_b2[j];

  // gh assignment: pair (2m, 2m+1) covers outputs m, m+128, m+256
  const int m  = tid >> 1;
  const int p2 = tid & 1;
  const float bh0 = gru_bh[m], bh1 = gru_bh[m+128], bh2 = gru_bh[m+256];
  const float4* wg0 = reinterpret_cast<const float4*>(whT + (size_t)m*128       + p2*64);
  const float4* wg1 = reinterpret_cast<const float4*>(whT + (size_t)(m+128)*128 + p2*64);
  const float4* wg2 = reinterpret_cast<const float4*>(whT + (size_t)(m+256)*128 + p2*64);

  float h = h0[b*128 + j];

  auto matvec = [&](const float* __restrict__ buf, const float (&wreg)[64], float bias) -> float {
    const float4* hv4 = reinterpret_cast<const float4*>(buf + p*64);
    float a0=0.f, a1=0.f, a2=0.f, a3=0.f;
    #pragma unroll
    for (int q=0;q<16;q++) {
      float4 hv = hv4[q];
      a0 = fmaf(hv.x, wreg[4*q+0], a0);
      a1 = fmaf(hv.y, wreg[4*q+1], a1);
      a2 = fmaf(hv.z, wreg[4*q+2], a2);
      a3 = fmaf(hv.w, wreg[4*q+3], a3);
    }
    float a = (a0+a1)+(a2+a3);
    a += __shfl_xor(a, 32);
    return fast_tanh(a + bias);
  };

  for (int t=0; t<64; t++) {
    const size_t bt = (size_t)b*64 + t;
    const float dt = inputs[bt*NIN + 10132];
    // prefetch gi for this step (used only in the GRU combine)
    const float gir = gi_ws[bt*384 + j];
    const float giz = gi_ws[bt*384 + 128 + j];
    const float gin = gi_ws[bt*384 + 256 + j];

    vbuf[j] = h;                       __syncthreads();   // (1)
    ubuf[j] = matvec(vbuf, w1h, b1);   __syncthreads();   // (2)
    const float k1 = matvec(ubuf, w2h, b2);
    vbuf[j] = fmaf(0.5f*dt, k1, h);    __syncthreads();   // (3)
    ubuf[j] = matvec(vbuf, w1h, b1);   __syncthreads();   // (4)
    const float k2 = matvec(ubuf, w2h, b2);
    vbuf[j] = fmaf(0.5f*dt, k2, h);    __syncthreads();   // (5)
    ubuf[j] = matvec(vbuf, w1h, b1);   __syncthreads();   // (6)
    const float k3 = matvec(ubuf, w2h, b2);
    vbuf[j] = fmaf(dt, k3, h);         __syncthreads();   // (7)
    ubuf[j] = matvec(vbuf, w1h, b1);   __syncthreads();   // (8)
    const float k4 = matvec(ubuf, w2h, b2);
    const float h_ode = fmaf(dt*(1.f/6.f), (k1 + 2.f*k2) + (2.f*k3 + k4), h);
    vbuf[j] = h_ode;                   __syncthreads();   // (9)

    // gh = h_ode @ gru_wh + gru_bh : 3 half-dots per thread, weights from L2
    {
      const float4* hv4 = reinterpret_cast<const float4*>(vbuf + p2*64);
      float g0=0.f, g1=0.f, g2=0.f;
      #pragma unroll
      for (int q=0;q<16;q++) {
        float4 hv = hv4[q];
        float4 A = wg0[q], B = wg1[q], C = wg2[q];
        g0 += hv.x*A.x + hv.y*A.y + hv.z*A.z + hv.w*A.w;
        g1 += hv.x*B.x + hv.y*B.y + hv.z*B.z + hv.w*B.w;
        g2 += hv.x*C.x + hv.y*C.y + hv.z*C.z + hv.w*C.w;
      }
      g0 += __shfl_xor(g0, 1);
      g1 += __shfl_xor(g1, 1);
      g2 += __shfl_xor(g2, 1);
      ghbuf[m]     = g0 + bh0;
      ghbuf[m+128] = g1 + bh1;
      ghbuf[m+256] = g2 + bh2;
    }
    __syncthreads();                                       // (10)

    const float r = fast_sig(gir + ghbuf[j]);
    const float z = fast_sig(giz + ghbuf[j+128]);
    const float n = fast_tanh(gin + r*ghbuf[j+256]);
    h = (1.f - z)*n + z*h_ode;
    if (p == 0) hs_ws[bt*128 + j] = h;
  }
  if (p == 0) hT_out[b*128 + j] = h;
}

// ---------------- K3: logits + mask + value ----------------
__global__ __launch_bounds__(256) void k_head(const float* __restrict__ hs_ws,
    const float* __restrict__ act_w, const float* __restrict__ act_b,
    const float* __restrict__ val_w, const float* __restrict__ val_b,
    const float* __restrict__ inputs, float* __restrict__ out_logits, float* __restrict__ out_val)
{
  __shared__ float xr[16][128];
  const int tid = threadIdx.x;
  const int bt0 = blockIdx.x * 16;
  for (int idx = tid; idx < 16*128; idx += 256) {
    int r = idx >> 7, f = idx & 127;
    xr[r][f] = hs_ws[(size_t)(bt0+r)*128 + f];
  }
  __syncthreads();
  if (tid < 132) {
    float acc[16];
    float bj = act_b[tid];
    #pragma unroll
    for (int r=0;r<16;r++) acc[r] = bj;
    for (int f=0; f<128; f++) {
      float wf = act_w[f*132 + tid];
      #pragma unroll
      for (int r=0;r<16;r++) acc[r] = fmaf(xr[r][f], wf, acc[r]);
    }
    #pragma unroll
    for (int r=0;r<16;r++) {
      float mval = inputs[(size_t)(bt0+r)*NIN + tid];
      out_logits[(size_t)(bt0+r)*132 + tid] = (mval == 0.f) ? -1e10f : acc[r];
    }
  } else if (tid >= 136 && tid < 152) {
    int r = tid - 136;
    float acc = val_b[0];
    for (int f=0; f<128; f++) acc = fmaf(xr[r][f], val_w[f], acc);
    out_val[bt0 + r] = acc;
  }
}

extern "C" void kernel_launch(void* const* d_in, const int* in_sizes, int n_in,
                              void* d_out, int out_size, void* d_ws, size_t ws_size,
                              hipStream_t stream) {
  (void)in_sizes; (void)n_in; (void)out_size; (void)ws_size;
  const float* inputs = (const float*)d_in[0];
  const float* h0     = (const float*)d_in[1];
  const float* fc_w   = (const float*)d_in[2];
  const float* fc_b   = (const float*)d_in[3];
  const float* gat_w  = (const float*)d_in[4];
  const float* a_src  = (const float*)d_in[5];
  const float* a_dst  = (const float*)d_in[6];
  const float* ode_w1 = (const float*)d_in[7];
  const float* ode_b1 = (const float*)d_in[8];
  const float* ode_w2 = (const float*)d_in[9];
  const float* ode_b2 = (const float*)d_in[10];
  const float* gru_wi = (const float*)d_in[11];
  const float* gru_wh = (const float*)d_in[12];
  const float* gru_bi = (const float*)d_in[13];
  const float* gru_bh = (const float*)d_in[14];
  const float* act_w  = (const float*)d_in[15];
  const float* act_b  = (const float*)d_in[16];
  const float* val_w  = (const float*)d_in[17];
  const float* val_b  = (const float*)d_in[18];

  float* ws   = (float*)d_ws;
  float* wh0  = ws;              // 2048*128
  float* sd   = ws + 262144;     // 2048*8
  float* xgat = ws + 278528;     // 2048*128
  float* gi   = ws + 540672;     // 2048*384
  float* whT  = ws + 1327104;    // 384*128
  float* hs   = ws + 1376256;    // 2048*128

  float* out        = (float*)d_out;
  float* out_logits = out;            // 2048*132
  float* out_hT     = out + 270336;   // 32*128
  float* out_val    = out + 274432;   // 2048

  k_fc_gat<<<dim3(128), dim3(256), 0, stream>>>(inputs, fc_w, fc_b, gat_w, a_src, a_dst, wh0, sd);
  k_alpha <<<dim3(2048), dim3(256), 0, stream>>>(inputs, wh0, sd, xgat);
  k_gi    <<<dim3(128), dim3(384), 0, stream>>>(xgat, gru_wi, gru_bi, gi);
  k_whT   <<<dim3(192), dim3(256), 0, stream>>>(gru_wh, whT);
  k_rnn   <<<dim3(32),  dim3(256), 0, stream>>>(inputs, h0, ode_w1, ode_b1, ode_w2, ode_b2,
                                                whT, gru_bh, gi, hs, out_hT);
  k_head  <<<dim3(128), dim3(256), 0, stream>>>(hs, act_w, act_b, val_w, val_b, inputs,
                                                out_logits, out_val);
}

// Round 3
// 337.767 us; speedup vs baseline: 3.5673x; 1.5745x over previous
//
#include <hip/hip_runtime.h>

#define NIN 10517

__device__ __forceinline__ float lrelu02(float x){ return x > 0.f ? x : 0.2f*x; }
__device__ __forceinline__ float fast_tanh(float x){ float e=__expf(2.f*x); return 1.f - 2.f/(e+1.f); }
__device__ __forceinline__ float fast_sig(float x){ return 1.f/(1.f+__expf(-x)); }

// ---------------- K1a: FC (384->256, relu) + Wh0 (256->128) + s,d per head ----------------
__global__ __launch_bounds__(256) void k_fc_gat(const float* __restrict__ inputs,
    const float* __restrict__ fc_w, const float* __restrict__ fc_b,
    const float* __restrict__ gat_w, const float* __restrict__ a_src, const float* __restrict__ a_dst,
    float* __restrict__ wh0_ws, float* __restrict__ sd_ws)
{
  __shared__ float xin[16][384];
  __shared__ float xfc[16][256];
  __shared__ float wh[16][128];
  const int tid = threadIdx.x;
  const int bt0 = blockIdx.x * 16;
  for (int idx = tid; idx < 16*384; idx += 256) {
    int r = idx / 384, f = idx - r*384;
    xin[r][f] = inputs[(size_t)(bt0+r)*NIN + 10133 + f];
  }
  __syncthreads();
  {
    float acc[16];
    float bj = fc_b[tid];
    #pragma unroll
    for (int r=0;r<16;r++) acc[r] = bj;
    for (int f=0; f<384; f++) {
      float wf = fc_w[f*256 + tid];
      #pragma unroll
      for (int r=0;r<16;r++) acc[r] = fmaf(xin[r][f], wf, acc[r]);
    }
    #pragma unroll
    for (int r=0;r<16;r++) xfc[r][tid] = fmaxf(acc[r], 0.f);
  }
  __syncthreads();
  {
    const int j2 = tid & 127, r0 = (tid >> 7) * 8;
    float acc[8];
    #pragma unroll
    for (int r=0;r<8;r++) acc[r] = 0.f;
    for (int f=0; f<256; f++) {
      float wf = gat_w[f*128 + j2];
      #pragma unroll
      for (int r=0;r<8;r++) acc[r] = fmaf(xfc[r0+r][f], wf, acc[r]);
    }
    #pragma unroll
    for (int r=0;r<8;r++) {
      wh[r0+r][j2] = acc[r];
      wh0_ws[(size_t)(bt0+r0+r)*128 + j2] = acc[r];
    }
  }
  __syncthreads();
  if (tid < 128) {
    const int r = tid >> 3, h = (tid >> 1) & 3, w = tid & 1;
    const float* av = w ? a_dst : a_src;
    float acc = 0.f;
    #pragma unroll
    for (int d=0; d<32; d++) acc = fmaf(wh[r][h*32+d], av[h*32+d], acc);
    sd_ws[(size_t)(bt0+r)*8 + w*4 + h] = acc;
  }
}

// ---------------- K1b: adjacency stats + closed-form alpha + x_gat ----------------
__global__ __launch_bounds__(256) void k_alpha(const float* __restrict__ inputs,
    const float* __restrict__ wh0_ws, const float* __restrict__ sd_ws, float* __restrict__ xgat_ws)
{
  __shared__ int cnt[100];
  __shared__ int a0f[100];
  __shared__ float alpha[4][100];
  __shared__ float wh0[128];
  __shared__ float sdl[8];
  const int tid = threadIdx.x;
  const size_t bt = blockIdx.x;
  if (tid < 128) wh0[tid] = wh0_ws[bt*128 + tid];
  if (tid < 8) sdl[tid] = sd_ws[bt*8 + tid];
  const float* adj = inputs + bt*NIN + 132;
  const int wv = tid >> 6, lane = tid & 63;
  for (int i = wv; i < 100; i += 4) {
    float v0 = adj[i*100 + lane];
    int pred0 = (lane != 0) && ((v0 > 0.f) || (lane == i));
    unsigned long long b0 = __ballot(pred0);
    int pred1 = 0;
    if (lane < 36) {
      float v1 = adj[i*100 + 64 + lane];
      pred1 = (v1 > 0.f) || ((64 + lane) == i);
    }
    unsigned long long b1 = __ballot(pred1);
    if (lane == 0) {
      cnt[i] = __popcll(b0) + __popcll(b1);
      a0f[i] = (v0 > 0.f) ? 1 : 0;
    }
  }
  __syncthreads();
  for (int idx = tid; idx < 400; idx += 256) {
    int h = idx / 100, i = idx - h*100;
    float s = sdl[h], d = sdl[4+h];
    float a;
    if (i == 0) {
      float ea = __expf(lrelu02(s + d));
      float eb = __expf(lrelu02(s));
      a = ea / (ea + (float)cnt[0] * eb);
    } else if (a0f[i]) {
      float ed = __expf(lrelu02(d));
      a = ed / (ed + (float)cnt[i]);
    } else {
      a = 0.f;
    }
    alpha[h][i] = a;
  }
  __syncthreads();
  if (tid < 128) {
    const int h = tid >> 5;
    const float w = wh0[tid];
    float sum = 0.f;
    for (int i=0;i<100;i++) {
      float t = alpha[h][i] * w;
      sum += (t > 0.f) ? t : (__expf(t) - 1.f);  // elu
    }
    xgat_ws[bt*128 + tid] = sum * 0.01f;  // mean over N=100
  }
}

// ---------------- K1c: gi = x_gat @ gru_wi + gru_bi ----------------
__global__ __launch_bounds__(384) void k_gi(const float* __restrict__ xgat_ws,
    const float* __restrict__ gru_wi, const float* __restrict__ gru_bi, float* __restrict__ gi_ws)
{
  __shared__ float xg[16][128];
  const int tid = threadIdx.x;
  const int bt0 = blockIdx.x * 16;
  for (int idx = tid; idx < 16*128; idx += 384) {
    int r = idx >> 7, f = idx & 127;
    xg[r][f] = xgat_ws[(size_t)(bt0+r)*128 + f];
  }
  __syncthreads();
  float acc[16];
  float bj = gru_bi[tid];
  #pragma unroll
  for (int r=0;r<16;r++) acc[r] = bj;
  for (int f=0; f<128; f++) {
    float wf = gru_wi[f*384 + tid];
    #pragma unroll
    for (int r=0;r<16;r++) acc[r] = fmaf(xg[r][f], wf, acc[r]);
  }
  #pragma unroll
  for (int r=0;r<16;r++) gi_ws[(size_t)(bt0+r)*384 + tid] = acc[r];
}

// ---------------- K1d: transpose gru_wh (128x384 -> 384x128) ----------------
__global__ void k_whT(const float* __restrict__ gru_wh, float* __restrict__ whT) {
  int idx = blockIdx.x * 256 + threadIdx.x;
  if (idx < 384*128) {
    int jj = idx >> 7, k = idx & 127;
    whT[idx] = gru_wh[k*384 + jj];
  }
}

// ---------------- K2: RK4-ODE + GRU scan ----------------
// 512 threads (8 waves), one block per batch element.
// Column j = (wave)*16 + (lane&15); K-quarter p4 = (lane>>4)&3.
// RK weights: 32+32 VGPRs/thread. GRU-hidden weights: thread j's quarter of
// rows (j, j+128, j+256) = 96 VGPRs -> ALL weights register-resident, zero
// per-step weight memory traffic. gh triplet lands exactly on the thread that
// needs it for the GRU combine -> no LDS round trip for gh (9 barriers/step).
// h-buffers padded: IDX(k) = (k>>5)*36 + (k&31) -> quarter-group broadcast
// reads hit disjoint bank quads (no conflicts). dt staged in LDS; hs buffered
// in LDS (32 KB) and dumped once; gi prefetched one step ahead under gh phase.
__global__ __launch_bounds__(512) void k_rnn(const float* __restrict__ inputs,
    const float* __restrict__ h0,
    const float* __restrict__ ode_w1, const float* __restrict__ ode_b1,
    const float* __restrict__ ode_w2, const float* __restrict__ ode_b2,
    const float* __restrict__ whT, const float* __restrict__ gru_bh,
    const float* __restrict__ gi_ws, float* __restrict__ hs_ws, float* __restrict__ hT_out)
{
  __shared__ __align__(16) float Abuf[144];
  __shared__ __align__(16) float Bbuf[144];
  __shared__ __align__(16) float Cbuf[144];
  __shared__ float dtbuf[64];
  __shared__ __align__(16) float hsbuf[64*128];
  const int tid = threadIdx.x;
  const int b = blockIdx.x;
  const int j  = ((tid >> 6) << 4) | (tid & 15);
  const int p4 = (tid >> 4) & 3;
  const int pj = ((j >> 5) * 36) + (j & 31);

  float w1q[32], w2q[32], wgA[32], wgB[32], wgC[32];
  #pragma unroll
  for (int k=0;k<32;k++) w1q[k] = ode_w1[(p4*32+k)*128 + j];
  #pragma unroll
  for (int k=0;k<32;k++) w2q[k] = ode_w2[(p4*32+k)*128 + j];
  {
    const size_t wb = (size_t)j*128 + p4*32;
    #pragma unroll
    for (int k=0;k<32;k++) wgA[k] = whT[wb + k];
    #pragma unroll
    for (int k=0;k<32;k++) wgB[k] = whT[wb + 128*128 + k];
    #pragma unroll
    for (int k=0;k<32;k++) wgC[k] = whT[wb + 256*128 + k];
  }
  const float b1 = ode_b1[j], b2 = ode_b2[j];
  const float bh0 = gru_bh[j], bh1 = gru_bh[j+128], bh2 = gru_bh[j+256];
  float h = h0[b*128 + j];
  if (tid < 64) dtbuf[tid] = inputs[((size_t)b*64 + tid)*NIN + 10132];
  if (p4 == 0) Cbuf[pj] = h;
  const float* gib = gi_ws + (size_t)b*64*384 + j;
  float gir = gib[0], giz = gib[128], gin = gib[256];
  __syncthreads();

  auto mv = [&](const float* __restrict__ src, const float (&wq)[32], float bias)->float {
    const float4* s4 = reinterpret_cast<const float4*>(src + p4*36);
    float a0=0.f,a1=0.f,a2=0.f,a3=0.f;
    #pragma unroll
    for (int q=0;q<8;q++){
      float4 hv = s4[q];
      a0 = fmaf(hv.x, wq[4*q+0], a0);
      a1 = fmaf(hv.y, wq[4*q+1], a1);
      a2 = fmaf(hv.z, wq[4*q+2], a2);
      a3 = fmaf(hv.w, wq[4*q+3], a3);
    }
    float a = (a0+a1)+(a2+a3);
    a += __shfl_xor(a, 16);
    a += __shfl_xor(a, 32);
    return fast_tanh(a + bias);
  };

  for (int t=0; t<64; t++) {
    const float dt = dtbuf[t];
    float u, k1, k2, k3, k4;
    u  = mv(Cbuf, w1q, b1); if (p4==0) Abuf[pj] = u;                      __syncthreads();
    k1 = mv(Abuf, w2q, b2); if (p4==0) Bbuf[pj] = fmaf(0.5f*dt, k1, h);   __syncthreads();
    u  = mv(Bbuf, w1q, b1); if (p4==0) Abuf[pj] = u;                      __syncthreads();
    k2 = mv(Abuf, w2q, b2); if (p4==0) Bbuf[pj] = fmaf(0.5f*dt, k2, h);   __syncthreads();
    u  = mv(Bbuf, w1q, b1); if (p4==0) Abuf[pj] = u;                      __syncthreads();
    k3 = mv(Abuf, w2q, b2); if (p4==0) Bbuf[pj] = fmaf(dt, k3, h);        __syncthreads();
    u  = mv(Bbuf, w1q, b1); if (p4==0) Abuf[pj] = u;                      __syncthreads();
    k4 = mv(Abuf, w2q, b2);
    const float h_ode = fmaf(dt*(1.f/6.f), (k1 + 2.f*k2) + (2.f*k3 + k4), h);
    if (p4==0) Bbuf[pj] = h_ode;                                          __syncthreads();

    // prefetch next step's gi under the gh phase
    const int tn = (t < 63) ? (t+1) : t;
    const float* gnb = gib + (size_t)tn*384;
    const float ngr = gnb[0], ngz = gnb[128], ngn = gnb[256];

    // gh = h_ode @ gru_wh (register-resident weights, quarter K-split)
    const float4* h4 = reinterpret_cast<const float4*>(Bbuf + p4*36);
    float g0=0.f, g1=0.f, g2=0.f;
    #pragma unroll
    for (int q=0;q<8;q++){
      float4 hv = h4[q];
      g0 = fmaf(hv.x, wgA[4*q+0], g0); g0 = fmaf(hv.y, wgA[4*q+1], g0);
      g0 = fmaf(hv.z, wgA[4*q+2], g0); g0 = fmaf(hv.w, wgA[4*q+3], g0);
      g1 = fmaf(hv.x, wgB[4*q+0], g1); g1 = fmaf(hv.y, wgB[4*q+1], g1);
      g1 = fmaf(hv.z, wgB[4*q+2], g1); g1 = fmaf(hv.w, wgB[4*q+3], g1);
      g2 = fmaf(hv.x, wgC[4*q+0], g2); g2 = fmaf(hv.y, wgC[4*q+1], g2);
      g2 = fmaf(hv.z, wgC[4*q+2], g2); g2 = fmaf(hv.w, wgC[4*q+3], g2);
    }
    g0 += __shfl_xor(g0, 16); g0 += __shfl_xor(g0, 32);
    g1 += __shfl_xor(g1, 16); g1 += __shfl_xor(g1, 32);
    g2 += __shfl_xor(g2, 16); g2 += __shfl_xor(g2, 32);

    const float r = fast_sig(gir + g0 + bh0);
    const float z = fast_sig(giz + g1 + bh1);
    const float n = fast_tanh(gin + r*(g2 + bh2));
    h = (1.f - z)*n + z*h_ode;
    if (p4==0) { Cbuf[pj] = h; hsbuf[t*128 + j] = h; }
    gir = ngr; giz = ngz; gin = ngn;
    __syncthreads();
  }
  if (p4==0) hT_out[b*128 + j] = h;
  // dump hs (all hsbuf writes synced by loop-end barrier)
  const float4* hv4 = reinterpret_cast<const float4*>(hsbuf);
  float4* o4 = reinterpret_cast<float4*>(hs_ws + (size_t)b*64*128);
  for (int idx = tid; idx < 64*128/4; idx += 512) o4[idx] = hv4[idx];
}

// ---------------- K3: logits + mask + value ----------------
__global__ __launch_bounds__(256) void k_head(const float* __restrict__ hs_ws,
    const float* __restrict__ act_w, const float* __restrict__ act_b,
    const float* __restrict__ val_w, const float* __restrict__ val_b,
    const float* __restrict__ inputs, float* __restrict__ out_logits, float* __restrict__ out_val)
{
  __shared__ float xr[16][128];
  const int tid = threadIdx.x;
  const int bt0 = blockIdx.x * 16;
  for (int idx = tid; idx < 16*128; idx += 256) {
    int r = idx >> 7, f = idx & 127;
    xr[r][f] = hs_ws[(size_t)(bt0+r)*128 + f];
  }
  __syncthreads();
  if (tid < 132) {
    float acc[16];
    float bj = act_b[tid];
    #pragma unroll
    for (int r=0;r<16;r++) acc[r] = bj;
    for (int f=0; f<128; f++) {
      float wf = act_w[f*132 + tid];
      #pragma unroll
      for (int r=0;r<16;r++) acc[r] = fmaf(xr[r][f], wf, acc[r]);
    }
    #pragma unroll
    for (int r=0;r<16;r++) {
      float mval = inputs[(size_t)(bt0+r)*NIN + tid];
      out_logits[(size_t)(bt0+r)*132 + tid] = (mval == 0.f) ? -1e10f : acc[r];
    }
  } else if (tid >= 136 && tid < 152) {
    int r = tid - 136;
    float acc = val_b[0];
    for (int f=0; f<128; f++) acc = fmaf(xr[r][f], val_w[f], acc);
    out_val[bt0 + r] = acc;
  }
}

extern "C" void kernel_launch(void* const* d_in, const int* in_sizes, int n_in,
                              void* d_out, int out_size, void* d_ws, size_t ws_size,
                              hipStream_t stream) {
  (void)in_sizes; (void)n_in; (void)out_size; (void)ws_size;
  const float* inputs = (const float*)d_in[0];
  const float* h0     = (const float*)d_in[1];
  const float* fc_w   = (const float*)d_in[2];
  const float* fc_b   = (const float*)d_in[3];
  const float* gat_w  = (const float*)d_in[4];
  const float* a_src  = (const float*)d_in[5];
  const float* a_dst  = (const float*)d_in[6];
  const float* ode_w1 = (const float*)d_in[7];
  const float* ode_b1 = (const float*)d_in[8];
  const float* ode_w2 = (const float*)d_in[9];
  const float* ode_b2 = (const float*)d_in[10];
  const float* gru_wi = (const float*)d_in[11];
  const float* gru_wh = (const float*)d_in[12];
  const float* gru_bi = (const float*)d_in[13];
  const float* gru_bh = (const float*)d_in[14];
  const float* act_w  = (const float*)d_in[15];
  const float* act_b  = (const float*)d_in[16];
  const float* val_w  = (const float*)d_in[17];
  const float* val_b  = (const float*)d_in[18];

  float* ws   = (float*)d_ws;
  float* wh0  = ws;              // 2048*128
  float* sd   = ws + 262144;     // 2048*8
  float* xgat = ws + 278528;     // 2048*128
  float* gi   = ws + 540672;     // 2048*384
  float* whT  = ws + 1327104;    // 384*128
  float* hs   = ws + 1376256;    // 2048*128

  float* out        = (float*)d_out;
  float* out_logits = out;            // 2048*132
  float* out_hT     = out + 270336;   // 32*128
  float* out_val    = out + 274432;   // 2048

  k_fc_gat<<<dim3(128), dim3(256), 0, stream>>>(inputs, fc_w, fc_b, gat_w, a_src, a_dst, wh0, sd);
  k_alpha <<<dim3(2048), dim3(256), 0, stream>>>(inputs, wh0, sd, xgat);
  k_gi    <<<dim3(128), dim3(384), 0, stream>>>(xgat, gru_wi, gru_bi, gi);
  k_whT   <<<dim3(192), dim3(256), 0, stream>>>(gru_wh, whT);
  k_rnn   <<<dim3(32),  dim3(512), 0, stream>>>(inputs, h0, ode_w1, ode_b1, ode_w2, ode_b2,
                                                whT, gru_bh, gi, hs, out_hT);
  k_head  <<<dim3(128), dim3(256), 0, stream>>>(hs, act_w, act_b, val_w, val_b, inputs,
                                                out_logits, out_val);
}